// Round 1
// baseline (2961.078 us; speedup 1.0000x reference)
//
#include <hip/hip_runtime.h>
#include <stdint.h>
#include <stddef.h>

#define BATCH 128
#define NFRAMES 256
#define EMBED 768
#define RES 2048
#define NCLS 1000

typedef __attribute__((ext_vector_type(8))) short bf16x8;
typedef __attribute__((ext_vector_type(4))) float f32x4;
typedef unsigned short u16;

__device__ inline u16 f2bf(float f) {
    union { float f; unsigned u; } v; v.f = f;
    unsigned r = v.u + 0x7FFFu + ((v.u >> 16) & 1u);
    return (u16)(r >> 16);
}
__device__ inline float bf2f(u16 h) {
    union { unsigned u; float f; } v; v.u = ((unsigned)h) << 16;
    return v.f;
}

// ---------------- fp32 -> bf16 convert, vectorized x4 ----------------
__global__ __launch_bounds__(256) void cvt_kernel(const float* __restrict__ in,
                                                  u16* __restrict__ out, int n4) {
    int i = blockIdx.x * blockDim.x + threadIdx.x;
    int stride = gridDim.x * blockDim.x;
    for (; i < n4; i += stride) {
        float4 v = ((const float4*)in)[i];
        ushort4 o;
        o.x = f2bf(v.x); o.y = f2bf(v.y); o.z = f2bf(v.z); o.w = f2bf(v.w);
        ((ushort4*)out)[i] = o;
    }
}

// ---------------- projection: u[t,b,r] = sum_e x[b,t,e] * W_in[r,e] ----------------
// A = x_bf16 [32768 x 768] (row-major, row = b*256+t), B = W_in_bf16 [2048 x 768]
// WG tile 128x128, 4 waves, each wave 64x64 (4x4 fragments of 16x16x32).
__global__ __launch_bounds__(256) void proj_kernel(const u16* __restrict__ xb,
                                                   const u16* __restrict__ win,
                                                   u16* __restrict__ u) {
    int lane = threadIdx.x & 63;
    int w = threadIdx.x >> 6;
    int wm = w >> 1, wn = w & 1;
    int m0 = blockIdx.x * 128 + wm * 64;
    int n0 = blockIdx.y * 128 + wn * 64;
    int lr = lane & 15;
    int lk = (lane >> 4) * 8;

    f32x4 acc[4][4];
#pragma unroll
    for (int i = 0; i < 4; i++)
#pragma unroll
        for (int j = 0; j < 4; j++) acc[i][j] = (f32x4)0.f;

    for (int kk = 0; kk < EMBED; kk += 32) {
        bf16x8 a[4], b[4];
#pragma unroll
        for (int i = 0; i < 4; i++)
            a[i] = *(const bf16x8*)(xb + (size_t)(m0 + i * 16 + lr) * EMBED + kk + lk);
#pragma unroll
        for (int j = 0; j < 4; j++)
            b[j] = *(const bf16x8*)(win + (size_t)(n0 + j * 16 + lr) * EMBED + kk + lk);
#pragma unroll
        for (int i = 0; i < 4; i++)
#pragma unroll
            for (int j = 0; j < 4; j++)
                acc[i][j] = __builtin_amdgcn_mfma_f32_16x16x32_bf16(a[i], b[j], acc[i][j], 0, 0, 0);
    }

    int rowbase = (lane >> 4) * 4;
#pragma unroll
    for (int i = 0; i < 4; i++) {
#pragma unroll
        for (int j = 0; j < 4; j++) {
#pragma unroll
            for (int q = 0; q < 4; q++) {
                int m = m0 + i * 16 + rowbase + q;   // row index = b*NFRAMES + t
                int n = n0 + j * 16 + lr;            // reservoir index
                int bb = m >> 8, tt = m & 255;
                u[((size_t)tt * BATCH + bb) * RES + n] = f2bf(acc[i][j][q]);
            }
        }
    }
}

// ---------------- one recurrence step ----------------
// new_state[b,r] = tanh( sum_k state[b,k]*res[r,k] + u_t[b,r] )
// grid (4, 64): 32x32 output tile per WG. 8 waves split K into 8 x 256.
__global__ __launch_bounds__(512) void step_kernel(const u16* __restrict__ sin,
                                                   const u16* __restrict__ res,
                                                   const u16* __restrict__ u_t,
                                                   u16* __restrict__ sout) {
    __shared__ float part[8][32][33];
    int lane = threadIdx.x & 63;
    int w = threadIdx.x >> 6;
    int m0 = blockIdx.x * 32;
    int n0 = blockIdx.y * 32;
    int k0 = w * 256;
    int lr = lane & 15;
    int lk = (lane >> 4) * 8;

    f32x4 acc[2][2];
#pragma unroll
    for (int i = 0; i < 2; i++)
#pragma unroll
        for (int j = 0; j < 2; j++) acc[i][j] = (f32x4)0.f;

#pragma unroll 2
    for (int kk = k0; kk < k0 + 256; kk += 32) {
        bf16x8 a[2], b[2];
#pragma unroll
        for (int i = 0; i < 2; i++)
            a[i] = *(const bf16x8*)(sin + (size_t)(m0 + i * 16 + lr) * RES + kk + lk);
#pragma unroll
        for (int j = 0; j < 2; j++)
            b[j] = *(const bf16x8*)(res + (size_t)(n0 + j * 16 + lr) * RES + kk + lk);
#pragma unroll
        for (int i = 0; i < 2; i++)
#pragma unroll
            for (int j = 0; j < 2; j++)
                acc[i][j] = __builtin_amdgcn_mfma_f32_16x16x32_bf16(a[i], b[j], acc[i][j], 0, 0, 0);
    }

    int rowbase = (lane >> 4) * 4;
#pragma unroll
    for (int i = 0; i < 2; i++)
#pragma unroll
        for (int j = 0; j < 2; j++)
#pragma unroll
            for (int q = 0; q < 4; q++)
                part[w][i * 16 + rowbase + q][j * 16 + lr] = acc[i][j][q];

    __syncthreads();

    for (int idx = threadIdx.x; idx < 1024; idx += 512) {
        int r = idx >> 5, c = idx & 31;
        float s = 0.f;
#pragma unroll
        for (int ww = 0; ww < 8; ww++) s += part[ww][r][c];
        float val = tanhf(s + bf2f(u_t[(size_t)(m0 + r) * RES + n0 + c]));
        sout[(size_t)(m0 + r) * RES + n0 + c] = f2bf(val);
    }
}

// ---------------- head: logits[b,c] = sum_r s[b,r]*W_out[c,r] + bias[c] ----------------
__global__ __launch_bounds__(512) void head_kernel(const u16* __restrict__ sin,
                                                   const u16* __restrict__ wout,
                                                   const float* __restrict__ bias,
                                                   float* __restrict__ out) {
    __shared__ float part[8][32][33];
    int lane = threadIdx.x & 63;
    int w = threadIdx.x >> 6;
    int m0 = blockIdx.x * 32;
    int n0 = blockIdx.y * 32;   // over padded 1024
    int k0 = w * 256;
    int lr = lane & 15;
    int lk = (lane >> 4) * 8;

    f32x4 acc[2][2];
#pragma unroll
    for (int i = 0; i < 2; i++)
#pragma unroll
        for (int j = 0; j < 2; j++) acc[i][j] = (f32x4)0.f;

    for (int kk = k0; kk < k0 + 256; kk += 32) {
        bf16x8 a[2], b[2];
#pragma unroll
        for (int i = 0; i < 2; i++)
            a[i] = *(const bf16x8*)(sin + (size_t)(m0 + i * 16 + lr) * RES + kk + lk);
#pragma unroll
        for (int j = 0; j < 2; j++) {
            int row = n0 + j * 16 + lr;
            if (row > NCLS - 1) row = NCLS - 1;  // clamp, result unused
            b[j] = *(const bf16x8*)(wout + (size_t)row * RES + kk + lk);
        }
#pragma unroll
        for (int i = 0; i < 2; i++)
#pragma unroll
            for (int j = 0; j < 2; j++)
                acc[i][j] = __builtin_amdgcn_mfma_f32_16x16x32_bf16(a[i], b[j], acc[i][j], 0, 0, 0);
    }

    int rowbase = (lane >> 4) * 4;
#pragma unroll
    for (int i = 0; i < 2; i++)
#pragma unroll
        for (int j = 0; j < 2; j++)
#pragma unroll
            for (int q = 0; q < 4; q++)
                part[w][i * 16 + rowbase + q][j * 16 + lr] = acc[i][j][q];

    __syncthreads();

    for (int idx = threadIdx.x; idx < 1024; idx += 512) {
        int r = idx >> 5, c = idx & 31;
        float s = 0.f;
#pragma unroll
        for (int ww = 0; ww < 8; ww++) s += part[ww][r][c];
        int cg = n0 + c;
        if (cg < NCLS)
            out[(size_t)(m0 + r) * NCLS + cg] = s + bias[cg];
    }
}

extern "C" void kernel_launch(void* const* d_in, const int* in_sizes, int n_in,
                              void* d_out, int out_size, void* d_ws, size_t ws_size,
                              hipStream_t stream) {
    const float* x_f    = (const float*)d_in[0];  // [128,256,768]
    const float* res_f  = (const float*)d_in[1];  // [2048,2048]
    const float* win_f  = (const float*)d_in[2];  // [2048,768]
    const float* wout_f = (const float*)d_in[3];  // [1000,2048]
    const float* bias   = (const float*)d_in[4];  // [1000]
    float* out = (float*)d_out;

    char* ws = (char*)d_ws;
    size_t off = 0;
    auto alloc = [&](size_t bytes) -> void* {
        void* p = ws + off;
        off += (bytes + 255) & ~(size_t)255;
        return p;
    };
    u16* res_b  = (u16*)alloc((size_t)RES * RES * 2);
    u16* win_b  = (u16*)alloc((size_t)RES * EMBED * 2);
    u16* wout_b = (u16*)alloc((size_t)NCLS * RES * 2);
    u16* x_b    = (u16*)alloc((size_t)BATCH * NFRAMES * EMBED * 2);
    u16* u      = (u16*)alloc((size_t)NFRAMES * BATCH * RES * 2);
    u16* s0     = (u16*)alloc((size_t)BATCH * RES * 2);
    u16* s1     = (u16*)alloc((size_t)BATCH * RES * 2);

    // weight / input conversion to bf16
    cvt_kernel<<<dim3(1024), dim3(256), 0, stream>>>(res_f, res_b, RES * RES / 4);
    cvt_kernel<<<dim3(512), dim3(256), 0, stream>>>(win_f, win_b, RES * EMBED / 4);
    cvt_kernel<<<dim3(512), dim3(256), 0, stream>>>(wout_f, wout_b, NCLS * RES / 4);
    cvt_kernel<<<dim3(2048), dim3(256), 0, stream>>>(x_f, x_b, BATCH * NFRAMES * EMBED / 4);

    // state0 = 0
    hipMemsetAsync(s0, 0, (size_t)BATCH * RES * 2, stream);

    // u[t,b,r] projection GEMM
    proj_kernel<<<dim3(256, 16), dim3(256), 0, stream>>>(x_b, win_b, u);

    // 256 sequential recurrence steps, ping-pong state
    for (int t = 0; t < NFRAMES; t++) {
        const u16* si = (t & 1) ? s1 : s0;
        u16* so = (t & 1) ? s0 : s1;
        step_kernel<<<dim3(4, 64), dim3(512), 0, stream>>>(si, res_b, u + (size_t)t * BATCH * RES, so);
    }

    // final state is in s0 (t=255 is odd -> wrote s0)
    head_kernel<<<dim3(4, 32), dim3(512), 0, stream>>>(s0, wout_b, bias, out);
}